// Round 8
// baseline (630.781 us; speedup 1.0000x reference)
//
#include <hip/hip_runtime.h>
#include <math.h>

#define B 16
#define N 2048
#define M 2048
#define BN (B * N)
#define LOG2E 1.4426950408889634f

#define CJ 128            // tile elements per LDS chunk
#define CH (CJ / 2)       // half-tile: 2-way interleaved inner loop
#define NCH (M / CJ)      // 16 chunks
#define TPB 128           // threads per block (2 waves)
#define RPT 4             // rows (or cols) per thread
#define RBLK (TPB * RPT)  // 512 rows per WG
// sweep grid: (NCH, N/RBLK, B) = (16, 4, 16) = 1024 WGs, 2048 waves (2/SIMD)

typedef float v2f __attribute__((ext_vector_type(2)));

#define EXP2F(x) __builtin_amdgcn_exp2f(x)
#define SQRTF(x) __builtin_amdgcn_sqrtf(x)

__device__ inline v2f exp2v(v2f a) {
    v2f r;
    r.x = EXP2F(a.x);
    r.y = EXP2F(a.y);
    return r;
}

// ---------------------------------------------------------------------------
// Pack xyz (stride-3) into float4 (x,y,z,|p|^2). 2*BN threads.
// ---------------------------------------------------------------------------
__global__ __launch_bounds__(256) void k_pack(const float* __restrict__ xyz1,
                                              const float* __restrict__ xyz2,
                                              float4* __restrict__ p1,
                                              float4* __restrict__ p2) {
    int idx = blockIdx.x * 256 + threadIdx.x;
    const float* s = (idx < BN) ? (xyz1 + 3 * (size_t)idx)
                                : (xyz2 + 3 * (size_t)(idx - BN));
    float x = s[0], y = s[1], z = s[2];
    float n = fmaf(x, x, fmaf(y, y, z * z));
    float4 v = make_float4(x, y, z, n);
    if (idx < BN) p1[idx] = v;
    else p2[idx - BN] = v;
}

// ---------------------------------------------------------------------------
// init: rl[0]=1, rr[0]=1, rs0=rs2=0, t1[1]=0, ss2[0]=0, cost=0.
// ---------------------------------------------------------------------------
__global__ __launch_bounds__(256) void k_init(float* __restrict__ rl0,
                                              float* __restrict__ rr0,
                                              float* __restrict__ rs0,
                                              float* __restrict__ rs2,
                                              float* __restrict__ t1b,
                                              float* __restrict__ ss20,
                                              float* __restrict__ cost) {
    int idx = blockIdx.x * 256 + threadIdx.x;
    rl0[idx] = 1.0f;
    rr0[idx] = 1.0f;
    rs0[idx] = 0.0f;
    rs2[idx] = 0.0f;
    t1b[idx] = 0.0f;
    ss20[idx] = 0.0f;
    if (idx < B) cost[idx] = 0.0f;
}

// ---------------------------------------------------------------------------
// rowsum for level 0 (rr==1): rs[i] += sum_j exp2(c2*d2(i,j))
// 4 rows/thread as two v2f chains; tile loop 2-way interleaved (t, t+CH).
// ---------------------------------------------------------------------------
__global__ __launch_bounds__(TPB, 2) void k_rowsum0(const float4* __restrict__ p1,
                                                    const float4* __restrict__ p2,
                                                    float* __restrict__ rs,
                                                    float c2) {
    __shared__ float4 tile4[CJ];  // xj, yj, zj, c2*nj
    const int b = blockIdx.z;
    const int tx = threadIdx.x;
    const int i0 = blockIdx.y * RBLK + tx;

    {
        int gj = b * M + blockIdx.x * CJ + tx;
        float4 f = p2[gj];
        tile4[tx] = make_float4(f.x, f.y, f.z, c2 * f.w);
    }
    __syncthreads();

    float4 fa = p1[b * N + i0];
    float4 fb = p1[b * N + i0 + TPB];
    float4 fc = p1[b * N + i0 + 2 * TPB];
    float4 fd = p1[b * N + i0 + 3 * TPB];
    const float m2c = -2.0f * c2;
    v2f Xp0 = {m2c * fa.x, m2c * fb.x}, Xp1 = {m2c * fc.x, m2c * fd.x};
    v2f Yp0 = {m2c * fa.y, m2c * fb.y}, Yp1 = {m2c * fc.y, m2c * fd.y};
    v2f Zp0 = {m2c * fa.z, m2c * fb.z}, Zp1 = {m2c * fc.z, m2c * fd.z};
    v2f ni0 = {c2 * fa.w, c2 * fb.w}, ni1 = {c2 * fc.w, c2 * fd.w};

    v2f acc0a = {0.0f, 0.0f}, acc1a = {0.0f, 0.0f};
    v2f acc0b = {0.0f, 0.0f}, acc1b = {0.0f, 0.0f};
#pragma unroll 4
    for (int t = 0; t < CH; ++t) {
        float4 qa = tile4[t];
        float4 qb = tile4[t + CH];
        v2f a0 = qa.x * Xp0 + (qa.y * Yp0 + (qa.z * Zp0 + (ni0 + qa.w)));
        v2f a1 = qa.x * Xp1 + (qa.y * Yp1 + (qa.z * Zp1 + (ni1 + qa.w)));
        v2f b0 = qb.x * Xp0 + (qb.y * Yp0 + (qb.z * Zp0 + (ni0 + qb.w)));
        v2f b1 = qb.x * Xp1 + (qb.y * Yp1 + (qb.z * Zp1 + (ni1 + qb.w)));
        acc0a += exp2v(a0);
        acc1a += exp2v(a1);
        acc0b += exp2v(b0);
        acc1b += exp2v(b1);
    }
    v2f acc0 = acc0a + acc0b, acc1 = acc1a + acc1b;
    atomicAdd(&rs[b * N + i0], acc0.x);
    atomicAdd(&rs[b * N + i0 + TPB], acc0.y);
    atomicAdd(&rs[b * N + i0 + 2 * TPB], acc1.x);
    atomicAdd(&rs[b * N + i0 + 3 * TPB], acc1.y);
}

// ---------------------------------------------------------------------------
// Column sweep (level l) + folded rl-update of level l-1 (tile phase).
// 4 cols/thread as two v2f chains; tile loop 2-way interleaved.
// ---------------------------------------------------------------------------
__global__ __launch_bounds__(TPB, 2) void k_colsum(const float4* __restrict__ p1,
                                                   const float4* __restrict__ p2,
                                                   const float* __restrict__ rl_in,
                                                   float* __restrict__ rl_out,
                                                   const float* __restrict__ rs_prev,
                                                   const float* __restrict__ rs_cur,
                                                   float* __restrict__ rs_zero,
                                                   const float* __restrict__ t1_in,
                                                   float* __restrict__ t1_zero,
                                                   const float* __restrict__ rr,
                                                   float* __restrict__ ss2_acc,
                                                   float cS) {
    __shared__ float4 tile4[CJ];  // xi, yi, zi, cS*ni
    __shared__ float tileA[CJ];   // a_i
    const int b = blockIdx.z;
    const int tx = threadIdx.x;
    const int j0 = blockIdx.y * RBLK + tx;

    {
        int gi = b * N + blockIdx.x * CJ + tx;
        float4 f = p1[gi];
        float rlo = rl_in[gi];
        float ap = rlo / (rs_prev[gi] + 1e-9f);
        float rln = fmaxf(rlo - ap * t1_in[gi], 0.0f);
        float a = rln / (rs_cur[gi] + 1e-9f);
        tile4[tx] = make_float4(f.x, f.y, f.z, cS * f.w);
        tileA[tx] = a;
        if (blockIdx.y == 0) {
            rl_out[gi] = rln;
            t1_zero[gi] = 0.0f;
            rs_zero[gi] = 0.0f;
        }
    }
    __syncthreads();

    float4 fa = p2[b * M + j0];
    float4 fb = p2[b * M + j0 + TPB];
    float4 fc = p2[b * M + j0 + 2 * TPB];
    float4 fd = p2[b * M + j0 + 3 * TPB];
    const float m2c = -2.0f * cS;
    v2f Xp0 = {m2c * fa.x, m2c * fb.x}, Xp1 = {m2c * fc.x, m2c * fd.x};
    v2f Yp0 = {m2c * fa.y, m2c * fb.y}, Yp1 = {m2c * fc.y, m2c * fd.y};
    v2f Zp0 = {m2c * fa.z, m2c * fb.z}, Zp1 = {m2c * fc.z, m2c * fd.z};
    v2f nj0 = {cS * fa.w, cS * fb.w}, nj1 = {cS * fc.w, cS * fd.w};

    v2f acc0a = {0.0f, 0.0f}, acc1a = {0.0f, 0.0f};
    v2f acc0b = {0.0f, 0.0f}, acc1b = {0.0f, 0.0f};
#pragma unroll 4
    for (int t = 0; t < CH; ++t) {
        float4 qa = tile4[t];
        float ava = tileA[t];
        float4 qb = tile4[t + CH];
        float avb = tileA[t + CH];
        v2f a0 = qa.x * Xp0 + (qa.y * Yp0 + (qa.z * Zp0 + (nj0 + qa.w)));
        v2f a1 = qa.x * Xp1 + (qa.y * Yp1 + (qa.z * Zp1 + (nj1 + qa.w)));
        v2f b0 = qb.x * Xp0 + (qb.y * Yp0 + (qb.z * Zp0 + (nj0 + qb.w)));
        v2f b1 = qb.x * Xp1 + (qb.y * Yp1 + (qb.z * Zp1 + (nj1 + qb.w)));
        acc0a += exp2v(a0) * ava;
        acc1a += exp2v(a1) * ava;
        acc0b += exp2v(b0) * avb;
        acc1b += exp2v(b1) * avb;
    }
    v2f acc0 = acc0a + acc0b, acc1 = acc1a + acc1b;
    atomicAdd(&ss2_acc[b * M + j0], acc0.x * rr[b * M + j0]);
    atomicAdd(&ss2_acc[b * M + j0 + TPB], acc0.y * rr[b * M + j0 + TPB]);
    atomicAdd(&ss2_acc[b * M + j0 + 2 * TPB], acc1.x * rr[b * M + j0 + 2 * TPB]);
    atomicAdd(&ss2_acc[b * M + j0 + 3 * TPB], acc1.y * rr[b * M + j0 + 3 * TPB]);
}

// ---------------------------------------------------------------------------
// Level-9 colsum, part 1 (exp==1): per-batch S = sum_i a_i + folded rl-update
// of level 8. Grid: B WGs x 256 threads.
// ---------------------------------------------------------------------------
__global__ __launch_bounds__(256) void k_suma(const float* __restrict__ rl_in,
                                              float* __restrict__ rl_out,
                                              const float* __restrict__ rs_prev,
                                              const float* __restrict__ rs_cur,
                                              const float* __restrict__ t1_in,
                                              float* __restrict__ S) {
    __shared__ float red[4];
    const int b = blockIdx.x;
    const int tx = threadIdx.x;
    float s = 0.0f;
#pragma unroll
    for (int k = 0; k < N / 256; ++k) {
        int gi = b * N + k * 256 + tx;
        float rlo = rl_in[gi];
        float ap = rlo / (rs_prev[gi] + 1e-9f);
        float rln = fmaxf(rlo - ap * t1_in[gi], 0.0f);
        rl_out[gi] = rln;
        s += rln / (rs_cur[gi] + 1e-9f);
    }
#pragma unroll
    for (int off = 32; off > 0; off >>= 1)
        s += __shfl_down(s, off, 64);
    if ((tx & 63) == 0) red[tx >> 6] = s;
    __syncthreads();
    if (tx == 0) S[b] = red[0] + red[1] + red[2] + red[3];
}

// Level-9 colsum, part 2: ss2[j] = rr[j] * S[b]  (direct store)
__global__ __launch_bounds__(256) void k_mulss2(const float* __restrict__ rr,
                                                const float* __restrict__ S,
                                                float* __restrict__ ss2_out) {
    int idx = blockIdx.x * 256 + threadIdx.x;
    ss2_out[idx] = rr[idx] * S[idx >> 11];
}

// ---------------------------------------------------------------------------
// Fused finrow(l) + rowsum(l+1). 4 rows/thread as two v2f chains; tile loop
// 2-way interleaved (t, t+CH) with separate accumulator sets.
// tile elem j: s=min(rr/(ss2+eps),1); q=rr*s; rrn=max(rr-ss2*s,0);
//   duties (y==0): rr_out[j]=rrn, zero ss2_zero[j].
// MODE 0 (l=0..7): cS=c2[l+1]; en=exp2(arg); el=en^4
// MODE 1 (l=8):    cS=c2[8];   el=exp2(arg); en=1
// MODE 2 (l=9):    cS=1 (arg==d2); el=1; no rs/t1/rr_out
// ---------------------------------------------------------------------------
template <int MODE>
__global__ __launch_bounds__(TPB, 2) void k_fused(const float4* __restrict__ p1,
                                                  const float4* __restrict__ p2,
                                                  const float* __restrict__ rr_in,
                                                  float* __restrict__ rr_out,
                                                  const float* __restrict__ ss2_in,
                                                  float* __restrict__ ss2_zero,
                                                  const float* __restrict__ rl_new,
                                                  const float* __restrict__ rs_cur,
                                                  float* __restrict__ rs_next,
                                                  float* __restrict__ t1_acc,
                                                  float* __restrict__ cost,
                                                  float cS, float invS) {
    __shared__ float4 tile4[CJ];  // xj, yj, zj, q
    __shared__ float2 tile2[CJ];  // rrn, cS*nj
    const int b = blockIdx.z;
    const int tx = threadIdx.x;
    const int i0 = blockIdx.y * RBLK + tx;

    {
        int gj = b * M + blockIdx.x * CJ + tx;
        float4 f = p2[gj];
        float rrv = rr_in[gj];
        float sv = ss2_in[gj];
        float s = fminf(rrv / (sv + 1e-9f), 1.0f);
        float q = rrv * s;
        float rrn = fmaxf(rrv - sv * s, 0.0f);
        tile4[tx] = make_float4(f.x, f.y, f.z, q);
        tile2[tx] = make_float2(rrn, cS * f.w);
        if (MODE != 2 && blockIdx.y == 0) {
            rr_out[gj] = rrn;
            ss2_zero[gj] = 0.0f;
        }
    }
    __syncthreads();

    float4 fa = p1[b * N + i0];
    float4 fb = p1[b * N + i0 + TPB];
    float4 fc = p1[b * N + i0 + 2 * TPB];
    float4 fd = p1[b * N + i0 + 3 * TPB];
    const float m2c = -2.0f * cS;
    v2f Xp0 = {m2c * fa.x, m2c * fb.x}, Xp1 = {m2c * fc.x, m2c * fd.x};
    v2f Yp0 = {m2c * fa.y, m2c * fb.y}, Yp1 = {m2c * fc.y, m2c * fd.y};
    v2f Zp0 = {m2c * fa.z, m2c * fb.z}, Zp1 = {m2c * fc.z, m2c * fd.z};
    v2f ni0 = {cS * fa.w, cS * fb.w}, ni1 = {cS * fc.w, cS * fd.w};

    v2f T10a = {0.0f, 0.0f}, T20a = {0.0f, 0.0f}, rs0a = {0.0f, 0.0f};
    v2f T11a = {0.0f, 0.0f}, T21a = {0.0f, 0.0f}, rs1a = {0.0f, 0.0f};
    v2f T10b = {0.0f, 0.0f}, T20b = {0.0f, 0.0f}, rs0b = {0.0f, 0.0f};
    v2f T11b = {0.0f, 0.0f}, T21b = {0.0f, 0.0f}, rs1b = {0.0f, 0.0f};
#pragma unroll 4
    for (int t = 0; t < CH; ++t) {
        float4 qa = tile4[t];
        float2 ra = tile2[t];
        float4 qb = tile4[t + CH];
        float2 rb = tile2[t + CH];
        v2f a0 = qa.x * Xp0 + (qa.y * Yp0 + (qa.z * Zp0 + (ni0 + ra.y)));
        v2f a1 = qa.x * Xp1 + (qa.y * Yp1 + (qa.z * Zp1 + (ni1 + ra.y)));
        v2f b0 = qb.x * Xp0 + (qb.y * Yp0 + (qb.z * Zp0 + (ni0 + rb.y)));
        v2f b1 = qb.x * Xp1 + (qb.y * Yp1 + (qb.z * Zp1 + (ni1 + rb.y)));

        v2f ela0, ela1, elb0, elb1, ena0, ena1, enb0, enb1;
        if (MODE == 0) {
            ena0 = exp2v(a0); ena1 = exp2v(a1);
            enb0 = exp2v(b0); enb1 = exp2v(b1);
            v2f s0 = ena0 * ena0, s1 = ena1 * ena1;
            v2f s2 = enb0 * enb0, s3 = enb1 * enb1;
            ela0 = s0 * s0; ela1 = s1 * s1;
            elb0 = s2 * s2; elb1 = s3 * s3;
        } else if (MODE == 1) {
            ela0 = exp2v(a0); ela1 = exp2v(a1);
            elb0 = exp2v(b0); elb1 = exp2v(b1);
        }

        v2f da0 = a0 * invS, da1 = a1 * invS;
        v2f db0 = b0 * invS, db1 = b1 * invS;
        da0.x = fmaxf(da0.x, 1e-12f); da0.y = fmaxf(da0.y, 1e-12f);
        da1.x = fmaxf(da1.x, 1e-12f); da1.y = fmaxf(da1.y, 1e-12f);
        db0.x = fmaxf(db0.x, 1e-12f); db0.y = fmaxf(db0.y, 1e-12f);
        db1.x = fmaxf(db1.x, 1e-12f); db1.y = fmaxf(db1.y, 1e-12f);
        v2f sa0, sa1, sb0, sb1;
        sa0.x = SQRTF(da0.x); sa0.y = SQRTF(da0.y);
        sa1.x = SQRTF(da1.x); sa1.y = SQRTF(da1.y);
        sb0.x = SQRTF(db0.x); sb0.y = SQRTF(db0.y);
        sb1.x = SQRTF(db1.x); sb1.y = SQRTF(db1.y);

        v2f wa0, wa1, wb0, wb1;
        if (MODE == 2) {
            wa0.x = qa.w; wa0.y = qa.w; wa1 = wa0;
            wb0.x = qb.w; wb0.y = qb.w; wb1 = wb0;
        } else {
            wa0 = ela0 * qa.w; wa1 = ela1 * qa.w;
            wb0 = elb0 * qb.w; wb1 = elb1 * qb.w;
        }
        T10a += wa0; T11a += wa1;
        T20a += wa0 * sa0; T21a += wa1 * sa1;
        T10b += wb0; T11b += wb1;
        T20b += wb0 * sb0; T21b += wb1 * sb1;
        if (MODE == 0) {
            rs0a += ena0 * ra.x; rs1a += ena1 * ra.x;
            rs0b += enb0 * rb.x; rs1b += enb1 * rb.x;
        } else if (MODE == 1) {
            rs0a.x += ra.x; rs0a.y += ra.x;
            rs1a.x += ra.x; rs1a.y += ra.x;
            rs0b.x += rb.x; rs0b.y += rb.x;
            rs1b.x += rb.x; rs1b.y += rb.x;
        }
    }

    v2f T10 = T10a + T10b, T11 = T11a + T11b;
    v2f T20 = T20a + T20b, T21 = T21a + T21b;
    v2f rs0v = rs0a + rs0b, rs1v = rs1a + rs1b;

    const int gi0 = b * N + i0;
    if (MODE != 2) {
        atomicAdd(&t1_acc[gi0], T10.x);
        atomicAdd(&t1_acc[gi0 + TPB], T10.y);
        atomicAdd(&t1_acc[gi0 + 2 * TPB], T11.x);
        atomicAdd(&t1_acc[gi0 + 3 * TPB], T11.y);
        atomicAdd(&rs_next[gi0], rs0v.x);
        atomicAdd(&rs_next[gi0 + TPB], rs0v.y);
        atomicAdd(&rs_next[gi0 + 2 * TPB], rs1v.x);
        atomicAdd(&rs_next[gi0 + 3 * TPB], rs1v.y);
    }

    float aa = rl_new[gi0] / (rs_cur[gi0] + 1e-9f);
    float ab = rl_new[gi0 + TPB] / (rs_cur[gi0 + TPB] + 1e-9f);
    float ac = rl_new[gi0 + 2 * TPB] / (rs_cur[gi0 + 2 * TPB] + 1e-9f);
    float ad = rl_new[gi0 + 3 * TPB] / (rs_cur[gi0 + 3 * TPB] + 1e-9f);
    float contrib = fmaf(aa, T20.x, fmaf(ab, T20.y, fmaf(ac, T21.x, ad * T21.y)));
#pragma unroll
    for (int off = 32; off > 0; off >>= 1)
        contrib += __shfl_down(contrib, off, 64);
    if ((threadIdx.x & 63) == 0) atomicAdd(&cost[b], contrib);
}

extern "C" void kernel_launch(void* const* d_in, const int* in_sizes, int n_in,
                              void* d_out, int out_size, void* d_ws, size_t ws_size,
                              hipStream_t stream) {
    const float* xyz1 = (const float*)d_in[0];
    const float* xyz2 = (const float*)d_in[1];
    float* cost = (float*)d_out;

    float* ws = (float*)d_ws;
    float* rl[2] = {ws + 0 * BN, ws + 1 * BN};
    float* rr[2] = {ws + 2 * BN, ws + 3 * BN};
    float* rs[3] = {ws + 4 * BN, ws + 5 * BN, ws + 6 * BN};
    float* ss2b[2] = {ws + 7 * BN, ws + 8 * BN};
    float* t1[2] = {ws + 9 * BN, ws + 10 * BN};
    float4* p1 = (float4*)(ws + 11 * BN);
    float4* p2 = (float4*)(ws + 15 * BN);
    float* S = ws + 19 * BN;

    static const float levels[10] = {-16384.0f, -4096.0f, -1024.0f, -256.0f,
                                     -64.0f,    -16.0f,   -4.0f,    -1.0f,
                                     -0.25f,    0.0f};
    float c2[10];
    for (int l = 0; l < 10; ++l) c2[l] = levels[l] * LOG2E;

    dim3 grid(NCH, N / RBLK, B);  // (16, 4, 16) = 1024 WGs
    dim3 blk(TPB);

    k_pack<<<dim3(2 * BN / 256), dim3(256), 0, stream>>>(xyz1, xyz2, p1, p2);
    k_init<<<dim3(BN / 256), dim3(256), 0, stream>>>(rl[0], rr[0], rs[0], rs[2],
                                                     t1[1], ss2b[0], cost);
    k_rowsum0<<<grid, blk, 0, stream>>>(p1, p2, rs[0], c2[0]);

    for (int l = 0; l < 10; ++l) {
        int p = l & 1;
        if (l < 9) {
            k_colsum<<<grid, blk, 0, stream>>>(
                p1, p2, rl[p], rl[1 - p], rs[(l + 2) % 3], rs[l % 3],
                rs[(l + 1) % 3], t1[1 - p], t1[p], rr[p], ss2b[p], c2[l]);
        } else {
            k_suma<<<dim3(B), dim3(256), 0, stream>>>(
                rl[p], rl[1 - p], rs[(l + 2) % 3], rs[l % 3], t1[1 - p], S);
            k_mulss2<<<dim3(BN / 256), dim3(256), 0, stream>>>(rr[p], S, ss2b[p]);
        }

        if (l <= 7) {
            float cS = c2[l + 1];
            k_fused<0><<<grid, blk, 0, stream>>>(
                p1, p2, rr[p], rr[1 - p], ss2b[p], ss2b[1 - p], rl[1 - p],
                rs[l % 3], rs[(l + 1) % 3], t1[p], cost, cS, 1.0f / cS);
        } else if (l == 8) {
            float cS = c2[8];
            k_fused<1><<<grid, blk, 0, stream>>>(
                p1, p2, rr[p], rr[1 - p], ss2b[p], ss2b[1 - p], rl[1 - p],
                rs[l % 3], rs[(l + 1) % 3], t1[p], cost, cS, 1.0f / cS);
        } else {
            k_fused<2><<<grid, blk, 0, stream>>>(
                p1, p2, rr[p], rr[1 - p], ss2b[p], ss2b[1 - p], rl[1 - p],
                rs[l % 3], rs[(l + 1) % 3], t1[p], cost, 1.0f, 1.0f);
        }
    }
}

// Round 9
// 616.859 us; speedup vs baseline: 1.0226x; 1.0226x over previous
//
#include <hip/hip_runtime.h>
#include <math.h>

#define B 16
#define N 2048
#define M 2048
#define BN (B * N)
#define LOG2E 1.4426950408889634f

#define CJ 128            // tile elements per LDS chunk
#define NCH (M / CJ)      // 16 chunks == number of partials
#define TPB 128           // threads per block (2 waves)
#define RPT 4             // rows (or cols) per thread
#define RBLK (TPB * RPT)  // 512 rows per WG
// sweep grid: (NCH, N/RBLK, B) = (16, 4, 16) = 1024 WGs, 2048 waves (2/SIMD)

typedef float v2f __attribute__((ext_vector_type(2)));

#define EXP2F(x) __builtin_amdgcn_exp2f(x)
#define SQRTF(x) __builtin_amdgcn_sqrtf(x)

__device__ inline v2f exp2v(v2f a) {
    v2f r;
    r.x = EXP2F(a.x);
    r.y = EXP2F(a.y);
    return r;
}

// ---------------------------------------------------------------------------
// Pack xyz (stride-3) into float4 (x,y,z,|p|^2). 2*BN threads.
// ---------------------------------------------------------------------------
__global__ __launch_bounds__(256) void k_pack(const float* __restrict__ xyz1,
                                              const float* __restrict__ xyz2,
                                              float4* __restrict__ p1,
                                              float4* __restrict__ p2) {
    int idx = blockIdx.x * 256 + threadIdx.x;
    const float* s = (idx < BN) ? (xyz1 + 3 * (size_t)idx)
                                : (xyz2 + 3 * (size_t)(idx - BN));
    float x = s[0], y = s[1], z = s[2];
    float n = fmaf(x, x, fmaf(y, y, z * z));
    float4 v = make_float4(x, y, z, n);
    if (idx < BN) p1[idx] = v;
    else p2[idx - BN] = v;
}

// ---------------------------------------------------------------------------
// init: rl[0]=1, rr[0]=1, rs0=rs2=0 (rs2 must be finite for l=0), t1[1]=0,
// cost=0.
// ---------------------------------------------------------------------------
__global__ __launch_bounds__(256) void k_init(float* __restrict__ rl0,
                                              float* __restrict__ rr0,
                                              float* __restrict__ rs0,
                                              float* __restrict__ rs2,
                                              float* __restrict__ t1b,
                                              float* __restrict__ cost) {
    int idx = blockIdx.x * 256 + threadIdx.x;
    rl0[idx] = 1.0f;
    rr0[idx] = 1.0f;
    rs0[idx] = 0.0f;
    rs2[idx] = 0.0f;
    t1b[idx] = 0.0f;
    if (idx < B) cost[idx] = 0.0f;
}

// ---------------------------------------------------------------------------
// Reduce 16 partials -> dense. rs only (after rowsum0).
// ---------------------------------------------------------------------------
__global__ __launch_bounds__(256) void k_reduce_rs(const float* __restrict__ rp,
                                                   float* __restrict__ rs_out) {
    int i = blockIdx.x * 256 + threadIdx.x;
    float s = 0.0f;
#pragma unroll
    for (int k = 0; k < NCH; ++k) s += rp[k * BN + i];
    rs_out[i] = s;
}

// Reduce 16 partials -> dense, for both t1 and rs (after fused levels 0..8).
__global__ __launch_bounds__(256) void k_reduce2(const float* __restrict__ tp,
                                                 float* __restrict__ t1_out,
                                                 const float* __restrict__ rp,
                                                 float* __restrict__ rs_out) {
    int i = blockIdx.x * 256 + threadIdx.x;
    float s = 0.0f, t = 0.0f;
#pragma unroll
    for (int k = 0; k < NCH; ++k) {
        t += tp[k * BN + i];
        s += rp[k * BN + i];
    }
    t1_out[i] = t;
    rs_out[i] = s;
}

// ---------------------------------------------------------------------------
// rowsum for level 0 (rr==1): rsp[chunk][i] = sum_{j in chunk} exp2(c2*d2)
// Plain stores (no atomics). 4 rows/thread as two v2f chains.
// ---------------------------------------------------------------------------
__global__ __launch_bounds__(TPB, 2) void k_rowsum0(const float4* __restrict__ p1,
                                                    const float4* __restrict__ p2,
                                                    float* __restrict__ rsp,
                                                    float c2) {
    __shared__ float4 tile4[CJ];  // xj, yj, zj, c2*nj
    const int b = blockIdx.z;
    const int tx = threadIdx.x;
    const int i0 = blockIdx.y * RBLK + tx;

    {
        int gj = b * M + blockIdx.x * CJ + tx;
        float4 f = p2[gj];
        tile4[tx] = make_float4(f.x, f.y, f.z, c2 * f.w);
    }
    __syncthreads();

    float4 fa = p1[b * N + i0];
    float4 fb = p1[b * N + i0 + TPB];
    float4 fc = p1[b * N + i0 + 2 * TPB];
    float4 fd = p1[b * N + i0 + 3 * TPB];
    const float m2c = -2.0f * c2;
    v2f Xp0 = {m2c * fa.x, m2c * fb.x}, Xp1 = {m2c * fc.x, m2c * fd.x};
    v2f Yp0 = {m2c * fa.y, m2c * fb.y}, Yp1 = {m2c * fc.y, m2c * fd.y};
    v2f Zp0 = {m2c * fa.z, m2c * fb.z}, Zp1 = {m2c * fc.z, m2c * fd.z};
    v2f ni0 = {c2 * fa.w, c2 * fb.w}, ni1 = {c2 * fc.w, c2 * fd.w};

    v2f acc0 = {0.0f, 0.0f}, acc1 = {0.0f, 0.0f};
#pragma unroll 8
    for (int t = 0; t < CJ; ++t) {
        float4 q4 = tile4[t];
        v2f arg0 = q4.x * Xp0 + (q4.y * Yp0 + (q4.z * Zp0 + (ni0 + q4.w)));
        v2f arg1 = q4.x * Xp1 + (q4.y * Yp1 + (q4.z * Zp1 + (ni1 + q4.w)));
        acc0 += exp2v(arg0);
        acc1 += exp2v(arg1);
    }
    const int pb = blockIdx.x * BN + b * N + i0;
    rsp[pb] = acc0.x;
    rsp[pb + TPB] = acc0.y;
    rsp[pb + 2 * TPB] = acc1.x;
    rsp[pb + 3 * TPB] = acc1.y;
}

// ---------------------------------------------------------------------------
// Column sweep (level l) + folded rl-update of level l-1 (tile phase).
// 4 cols/thread as two v2f chains; writes ss2 PARTIALS (plain stores).
// ---------------------------------------------------------------------------
__global__ __launch_bounds__(TPB, 2) void k_colsum(const float4* __restrict__ p1,
                                                   const float4* __restrict__ p2,
                                                   const float* __restrict__ rl_in,
                                                   float* __restrict__ rl_out,
                                                   const float* __restrict__ rs_prev,
                                                   const float* __restrict__ rs_cur,
                                                   const float* __restrict__ t1_in,
                                                   const float* __restrict__ rr,
                                                   float* __restrict__ ss2p,
                                                   float cS) {
    __shared__ float4 tile4[CJ];  // xi, yi, zi, cS*ni
    __shared__ float tileA[CJ];   // a_i
    const int b = blockIdx.z;
    const int tx = threadIdx.x;
    const int j0 = blockIdx.y * RBLK + tx;

    {
        int gi = b * N + blockIdx.x * CJ + tx;
        float4 f = p1[gi];
        float rlo = rl_in[gi];
        float ap = rlo / (rs_prev[gi] + 1e-9f);
        float rln = fmaxf(rlo - ap * t1_in[gi], 0.0f);
        float a = rln / (rs_cur[gi] + 1e-9f);
        tile4[tx] = make_float4(f.x, f.y, f.z, cS * f.w);
        tileA[tx] = a;
        if (blockIdx.y == 0) rl_out[gi] = rln;
    }
    __syncthreads();

    float4 fa = p2[b * M + j0];
    float4 fb = p2[b * M + j0 + TPB];
    float4 fc = p2[b * M + j0 + 2 * TPB];
    float4 fd = p2[b * M + j0 + 3 * TPB];
    const float m2c = -2.0f * cS;
    v2f Xp0 = {m2c * fa.x, m2c * fb.x}, Xp1 = {m2c * fc.x, m2c * fd.x};
    v2f Yp0 = {m2c * fa.y, m2c * fb.y}, Yp1 = {m2c * fc.y, m2c * fd.y};
    v2f Zp0 = {m2c * fa.z, m2c * fb.z}, Zp1 = {m2c * fc.z, m2c * fd.z};
    v2f nj0 = {cS * fa.w, cS * fb.w}, nj1 = {cS * fc.w, cS * fd.w};

    v2f acc0 = {0.0f, 0.0f}, acc1 = {0.0f, 0.0f};
#pragma unroll 8
    for (int t = 0; t < CJ; ++t) {
        float4 q4 = tile4[t];
        float av = tileA[t];
        v2f arg0 = q4.x * Xp0 + (q4.y * Yp0 + (q4.z * Zp0 + (nj0 + q4.w)));
        v2f arg1 = q4.x * Xp1 + (q4.y * Yp1 + (q4.z * Zp1 + (nj1 + q4.w)));
        acc0 += exp2v(arg0) * av;
        acc1 += exp2v(arg1) * av;
    }
    const int gj = b * M + j0;
    const int pb = blockIdx.x * BN + gj;
    ss2p[pb] = acc0.x * rr[gj];
    ss2p[pb + TPB] = acc0.y * rr[gj + TPB];
    ss2p[pb + 2 * TPB] = acc1.x * rr[gj + 2 * TPB];
    ss2p[pb + 3 * TPB] = acc1.y * rr[gj + 3 * TPB];
}

// ---------------------------------------------------------------------------
// Level-9 colsum, part 1 (exp==1): per-batch S = sum_i a_i + folded rl-update
// of level 8. Grid: B WGs x 256 threads.
// ---------------------------------------------------------------------------
__global__ __launch_bounds__(256) void k_suma(const float* __restrict__ rl_in,
                                              float* __restrict__ rl_out,
                                              const float* __restrict__ rs_prev,
                                              const float* __restrict__ rs_cur,
                                              const float* __restrict__ t1_in,
                                              float* __restrict__ S) {
    __shared__ float red[4];
    const int b = blockIdx.x;
    const int tx = threadIdx.x;
    float s = 0.0f;
#pragma unroll
    for (int k = 0; k < N / 256; ++k) {
        int gi = b * N + k * 256 + tx;
        float rlo = rl_in[gi];
        float ap = rlo / (rs_prev[gi] + 1e-9f);
        float rln = fmaxf(rlo - ap * t1_in[gi], 0.0f);
        rl_out[gi] = rln;
        s += rln / (rs_cur[gi] + 1e-9f);
    }
#pragma unroll
    for (int off = 32; off > 0; off >>= 1)
        s += __shfl_down(s, off, 64);
    if ((tx & 63) == 0) red[tx >> 6] = s;
    __syncthreads();
    if (tx == 0) S[b] = red[0] + red[1] + red[2] + red[3];
}

// Level-9 colsum, part 2: ss2d[j] = rr[j] * S[b]  (direct dense store)
__global__ __launch_bounds__(256) void k_mulss2(const float* __restrict__ rr,
                                                const float* __restrict__ S,
                                                float* __restrict__ ss2_out) {
    int idx = blockIdx.x * 256 + threadIdx.x;
    ss2_out[idx] = rr[idx] * S[idx >> 11];
}

// ---------------------------------------------------------------------------
// Fused finrow(l) + rowsum(l+1). 4 rows/thread as two v2f chains.
// Tile phase: MODE 0/1 sum ss2 over 16 partials; MODE 2 reads dense ss2d.
// Epilogue: t1/rs written as PARTIALS (plain stores); only cost is atomic.
// MODE 0 (l=0..7): cS=c2[l+1]; en=exp2(arg); el=en^4
// MODE 1 (l=8):    cS=c2[8];   el=exp2(arg); en=1
// MODE 2 (l=9):    cS=1 (arg==d2); el=1; no t1/rs/rr_out
// ---------------------------------------------------------------------------
template <int MODE>
__global__ __launch_bounds__(TPB, 2) void k_fused(const float4* __restrict__ p1,
                                                  const float4* __restrict__ p2,
                                                  const float* __restrict__ rr_in,
                                                  float* __restrict__ rr_out,
                                                  const float* __restrict__ ss2_in,
                                                  const float* __restrict__ rl_new,
                                                  const float* __restrict__ rs_cur,
                                                  float* __restrict__ rsp,
                                                  float* __restrict__ t1p,
                                                  float* __restrict__ cost,
                                                  float cS, float invS) {
    __shared__ float4 tile4[CJ];  // xj, yj, zj, q
    __shared__ float2 tile2[CJ];  // rrn, cS*nj
    const int b = blockIdx.z;
    const int tx = threadIdx.x;
    const int i0 = blockIdx.y * RBLK + tx;

    {
        int gj = b * M + blockIdx.x * CJ + tx;
        float4 f = p2[gj];
        float rrv = rr_in[gj];
        float sv;
        if (MODE == 2) {
            sv = ss2_in[gj];  // dense (from k_mulss2)
        } else {
            sv = 0.0f;
#pragma unroll
            for (int k = 0; k < NCH; ++k) sv += ss2_in[k * BN + gj];
        }
        float s = fminf(rrv / (sv + 1e-9f), 1.0f);
        float q = rrv * s;
        float rrn = fmaxf(rrv - sv * s, 0.0f);
        tile4[tx] = make_float4(f.x, f.y, f.z, q);
        tile2[tx] = make_float2(rrn, cS * f.w);
        if (MODE != 2 && blockIdx.y == 0) rr_out[gj] = rrn;
    }
    __syncthreads();

    float4 fa = p1[b * N + i0];
    float4 fb = p1[b * N + i0 + TPB];
    float4 fc = p1[b * N + i0 + 2 * TPB];
    float4 fd = p1[b * N + i0 + 3 * TPB];
    const float m2c = -2.0f * cS;
    v2f Xp0 = {m2c * fa.x, m2c * fb.x}, Xp1 = {m2c * fc.x, m2c * fd.x};
    v2f Yp0 = {m2c * fa.y, m2c * fb.y}, Yp1 = {m2c * fc.y, m2c * fd.y};
    v2f Zp0 = {m2c * fa.z, m2c * fb.z}, Zp1 = {m2c * fc.z, m2c * fd.z};
    v2f ni0 = {cS * fa.w, cS * fb.w}, ni1 = {cS * fc.w, cS * fd.w};

    v2f T10 = {0.0f, 0.0f}, T20 = {0.0f, 0.0f}, rs0v = {0.0f, 0.0f};
    v2f T11 = {0.0f, 0.0f}, T21 = {0.0f, 0.0f}, rs1v = {0.0f, 0.0f};
#pragma unroll 8
    for (int t = 0; t < CJ; ++t) {
        float4 q4 = tile4[t];
        float2 rn = tile2[t];
        v2f arg0 = q4.x * Xp0 + (q4.y * Yp0 + (q4.z * Zp0 + (ni0 + rn.y)));
        v2f arg1 = q4.x * Xp1 + (q4.y * Yp1 + (q4.z * Zp1 + (ni1 + rn.y)));
        v2f el0, el1, en0, en1;
        if (MODE == 0) {
            en0 = exp2v(arg0);
            en1 = exp2v(arg1);
            v2f e20 = en0 * en0, e21 = en1 * en1;
            el0 = e20 * e20;
            el1 = e21 * e21;
        } else if (MODE == 1) {
            el0 = exp2v(arg0);
            el1 = exp2v(arg1);
        }
        v2f d20 = arg0 * invS, d21 = arg1 * invS;
        d20.x = fmaxf(d20.x, 1e-12f);
        d20.y = fmaxf(d20.y, 1e-12f);
        d21.x = fmaxf(d21.x, 1e-12f);
        d21.y = fmaxf(d21.y, 1e-12f);
        v2f sd0, sd1;
        sd0.x = SQRTF(d20.x);
        sd0.y = SQRTF(d20.y);
        sd1.x = SQRTF(d21.x);
        sd1.y = SQRTF(d21.y);
        v2f wq0, wq1;
        if (MODE == 2) {
            wq0.x = q4.w; wq0.y = q4.w;
            wq1.x = q4.w; wq1.y = q4.w;
        } else {
            wq0 = el0 * q4.w;
            wq1 = el1 * q4.w;
        }
        T10 += wq0;
        T11 += wq1;
        T20 += wq0 * sd0;
        T21 += wq1 * sd1;
        if (MODE == 0) {
            rs0v += en0 * rn.x;
            rs1v += en1 * rn.x;
        } else if (MODE == 1) {
            rs0v += rn.x;
            rs1v += rn.x;
        }
    }

    const int gi0 = b * N + i0;
    if (MODE != 2) {
        const int pb = blockIdx.x * BN + gi0;
        t1p[pb] = T10.x;
        t1p[pb + TPB] = T10.y;
        t1p[pb + 2 * TPB] = T11.x;
        t1p[pb + 3 * TPB] = T11.y;
        rsp[pb] = rs0v.x;
        rsp[pb + TPB] = rs0v.y;
        rsp[pb + 2 * TPB] = rs1v.x;
        rsp[pb + 3 * TPB] = rs1v.y;
    }

    float aa = rl_new[gi0] / (rs_cur[gi0] + 1e-9f);
    float ab = rl_new[gi0 + TPB] / (rs_cur[gi0 + TPB] + 1e-9f);
    float ac = rl_new[gi0 + 2 * TPB] / (rs_cur[gi0 + 2 * TPB] + 1e-9f);
    float ad = rl_new[gi0 + 3 * TPB] / (rs_cur[gi0 + 3 * TPB] + 1e-9f);
    float contrib = fmaf(aa, T20.x, fmaf(ab, T20.y, fmaf(ac, T21.x, ad * T21.y)));
#pragma unroll
    for (int off = 32; off > 0; off >>= 1)
        contrib += __shfl_down(contrib, off, 64);
    if ((threadIdx.x & 63) == 0) atomicAdd(&cost[b], contrib);
}

extern "C" void kernel_launch(void* const* d_in, const int* in_sizes, int n_in,
                              void* d_out, int out_size, void* d_ws, size_t ws_size,
                              hipStream_t stream) {
    const float* xyz1 = (const float*)d_in[0];
    const float* xyz2 = (const float*)d_in[1];
    float* cost = (float*)d_out;

    float* ws = (float*)d_ws;
    float* rl[2] = {ws + 0 * BN, ws + 1 * BN};
    float* rr[2] = {ws + 2 * BN, ws + 3 * BN};
    float* rs[3] = {ws + 4 * BN, ws + 5 * BN, ws + 6 * BN};
    float* t1[2] = {ws + 7 * BN, ws + 8 * BN};
    float* ss2d = ws + 9 * BN;
    float4* p1 = (float4*)(ws + 10 * BN);
    float4* p2 = (float4*)(ws + 14 * BN);
    float* S = ws + 18 * BN;
    float* t1p = ws + 18 * BN + 64;                 // 16*BN
    float* rsp = t1p + (size_t)NCH * BN;            // 16*BN
    float* ss2p = rsp + (size_t)NCH * BN;           // 16*BN

    static const float levels[10] = {-16384.0f, -4096.0f, -1024.0f, -256.0f,
                                     -64.0f,    -16.0f,   -4.0f,    -1.0f,
                                     -0.25f,    0.0f};
    float c2[10];
    for (int l = 0; l < 10; ++l) c2[l] = levels[l] * LOG2E;

    dim3 grid(NCH, N / RBLK, B);  // (16, 4, 16) = 1024 WGs
    dim3 blk(TPB);
    dim3 rgrid(BN / 256), rblk(256);

    k_pack<<<dim3(2 * BN / 256), rblk, 0, stream>>>(xyz1, xyz2, p1, p2);
    k_init<<<rgrid, rblk, 0, stream>>>(rl[0], rr[0], rs[0], rs[2], t1[1], cost);
    k_rowsum0<<<grid, blk, 0, stream>>>(p1, p2, rsp, c2[0]);
    k_reduce_rs<<<rgrid, rblk, 0, stream>>>(rsp, rs[0]);

    for (int l = 0; l < 10; ++l) {
        int p = l & 1;
        if (l < 9) {
            k_colsum<<<grid, blk, 0, stream>>>(
                p1, p2, rl[p], rl[1 - p], rs[(l + 2) % 3], rs[l % 3],
                t1[1 - p], rr[p], ss2p, c2[l]);
        } else {
            k_suma<<<dim3(B), rblk, 0, stream>>>(
                rl[p], rl[1 - p], rs[(l + 2) % 3], rs[l % 3], t1[1 - p], S);
            k_mulss2<<<rgrid, rblk, 0, stream>>>(rr[p], S, ss2d);
        }

        if (l <= 7) {
            float cS = c2[l + 1];
            k_fused<0><<<grid, blk, 0, stream>>>(
                p1, p2, rr[p], rr[1 - p], ss2p, rl[1 - p], rs[l % 3],
                rsp, t1p, cost, cS, 1.0f / cS);
        } else if (l == 8) {
            float cS = c2[8];
            k_fused<1><<<grid, blk, 0, stream>>>(
                p1, p2, rr[p], rr[1 - p], ss2p, rl[1 - p], rs[l % 3],
                rsp, t1p, cost, cS, 1.0f / cS);
        } else {
            k_fused<2><<<grid, blk, 0, stream>>>(
                p1, p2, rr[p], rr[1 - p], ss2d, rl[1 - p], rs[l % 3],
                rsp, t1p, cost, 1.0f, 1.0f);
        }

        if (l <= 8) {
            k_reduce2<<<rgrid, rblk, 0, stream>>>(t1p, t1[p], rsp,
                                                  rs[(l + 1) % 3]);
        }
    }
}